// Round 14
// baseline (68.803 us; speedup 1.0000x reference)
//
#include <hip/hip_runtime.h>

#define CROP 14
#define NPOS (CROP * CROP)       // 196
#define CHANNELS 256
#define CPB 16                   // channels per block (16 blocks per proposal)
#define NBLK (CHANNELS / CPB)    // 16
#define LDS_FLOATS 4096          // 16 KiB
#define SLOT_MAX 392             // fallback threshold (geometry keeps SLOT below this)
#define NQUAD 49
#define NSUB 5
#define TBL_STRIDE 4096          // bytes per proposal in the d_ws table

typedef float __attribute__((ext_vector_type(4))) fx4;

struct __align__(16) Hdr {
    int lvl, x_lo, y_lo, WW;
    int WH, SLOT, bimg, kR;
    unsigned Mww;                 // magic divisor: floor(lane/WW) = (lane*Mww)>>32
    int kRWW, CG, pad;
};                                // 48 B

struct Ent { int a0; float w00, w01, w10, w11; };   // 20 B

// ---------------- Kernel A: per-proposal table precompute -----------------
__global__ __launch_bounds__(256) void precompute_kernel(
    const float* __restrict__ props, char* __restrict__ tbl)
{
    const int n   = blockIdx.x;
    const int tid = threadIdx.x;

    const float bx0 = props[n * 7 + 1];
    const float by0 = props[n * 7 + 2];
    const float bx1 = props[n * 7 + 3];
    const float by1 = props[n * 7 + 4];

    const float sz = sqrtf((bx1 - bx0) * (by1 - by0));
    int lvl = 0; float bd = fabsf(sz - 8.0f), d;
    d = fabsf(sz - 16.0f); if (d < bd) { bd = d; lvl = 1; }
    d = fabsf(sz - 32.0f); if (d < bd) { bd = d; lvl = 2; }
    d = fabsf(sz - 64.0f); if (d < bd) { bd = d; lvl = 3; }

    const int   H     = 256 >> lvl;
    const float scale = 0.25f / (float)(1 << lvl);

    const float xs0 = bx0 * scale, xs1 = bx1 * scale;
    const float ys0 = by0 * scale, ys1 = by1 * scale;
    const int x_lo = min((int)floorf(xs0), H - 2);
    const int x_hi = min((int)floorf(xs1), H - 2) + 1;
    const int y_lo = min((int)floorf(ys0), H - 2);
    const int y_hi = min((int)floorf(ys1), H - 2) + 1;
    const int WW = x_hi - x_lo + 1;
    const int WH = y_hi - y_lo + 1;
    const int SLOT = WH * WW;

    char* tp = tbl + (size_t)n * TBL_STRIDE;

    if (tid == 0) {
        Hdr h;
        h.lvl = lvl; h.x_lo = x_lo; h.y_lo = y_lo; h.WW = WW;
        h.WH = WH; h.SLOT = SLOT; h.bimg = (int)props[n * 7 + 0];
        h.kR = 64 / WW;
        h.Mww = (unsigned)((0x100000000ULL + (unsigned)WW - 1) / (unsigned)WW);
        h.kRWW = h.kR * WW;
        int CG = LDS_FLOATS / SLOT; if (CG > CPB) CG = CPB;
        h.CG = CG; h.pad = 0;
        *reinterpret_cast<Hdr*>(tp) = h;
    }

    if (tid < NPOS) {
        const int py = tid / CROP;
        const int px = tid - py * CROP;

        const float gy  = (float)py / 13.0f;
        const float ysv = ys0 + (ys1 - ys0) * gy;
        const float yfv = floorf(ysv);
        const float ly  = ysv - yfv;                  // unclamped (ref)
        const int   yi0 = min((int)yfv, H - 1);       // ysv >= 0
        const bool  ycl = (yi0 == H - 1);
        const int   byl = (ycl ? H - 2 : yi0) - y_lo;
        const float wy0 = ycl ? 0.0f : 1.0f - ly;
        const float wy1 = ycl ? 1.0f : ly;

        const float gx  = (float)px / 13.0f;
        const float xsv = xs0 + (xs1 - xs0) * gx;
        const float xfv = floorf(xsv);
        const float lx  = xsv - xfv;
        const int   xi0 = min((int)xfv, H - 1);
        const bool  xcl = (xi0 == H - 1);
        const int   bxl = (xcl ? H - 2 : xi0) - x_lo;
        const float wx0 = xcl ? 0.0f : 1.0f - lx;
        const float wx1 = xcl ? 1.0f : lx;

        Ent e;
        e.a0  = byl * WW + bxl;
        e.w00 = wy0 * wx0; e.w01 = wy0 * wx1;
        e.w10 = wy1 * wx0; e.w11 = wy1 * wx1;
        *reinterpret_cast<Ent*>(tp + 64 + tid * (int)sizeof(Ent)) = e;
    }
}

// ---------------- Kernel B: main (table-driven) ---------------------------
__global__ __launch_bounds__(256) void crop_roi_main(
    const float* __restrict__ p2, const float* __restrict__ p3,
    const float* __restrict__ p4, const float* __restrict__ p5,
    const float* __restrict__ props, const char* __restrict__ tbl,
    float* __restrict__ out)
{
    const int blk   = blockIdx.x;
    const int n     = blk >> 4;
    const int chunk = blk & 15;
    const int tid   = threadIdx.x;
    const int lane  = tid & 63;
    const int wid   = tid >> 6;

    __shared__ float win[LDS_FLOATS];

    const char* tp = tbl + (size_t)n * TBL_STRIDE;
    const Hdr h = *reinterpret_cast<const Hdr*>(tp);

    const int   H  = 256 >> h.lvl;
    const int   HW = H * H;
    const float* fp = (h.lvl == 0) ? p2 : (h.lvl == 1) ? p3
                    : (h.lvl == 2) ? p4 : p5;
    const float* base = fp + (size_t)h.bimg * CHANNELS * HW
                           + (size_t)(chunk * CPB) * HW;
    const int WW = h.WW, WH = h.WH, SLOT = h.SLOT;

    float* __restrict__ outp = out + ((size_t)n * CHANNELS + chunk * CPB) * NPOS;

    if (SLOT <= SLOT_MAX) {
        const int q   = tid % NQUAD;
        const int sub = tid / NQUAD;
        const bool smp = (sub < NSUB);

        // 4 table entries (80 contiguous bytes, L2-resident)
        const Ent* ep = reinterpret_cast<const Ent*>(tp + 64) + 4 * q;
        int   a0[4]; float w00[4], w01[4], w10[4], w11[4];
        #pragma unroll
        for (int j = 0; j < 4; ++j) {
            const Ent e = ep[j];
            a0[j] = e.a0; w00[j] = e.w00; w01[j] = e.w01;
            w10[j] = e.w10; w11[j] = e.w11;
        }
        float* __restrict__ opq = outp + 4 * q;

        // staging lane geometry (magic-mul division)
        const int  wyo  = (int)(((unsigned long long)(unsigned)lane * h.Mww) >> 32);
        const int  wxl  = lane - wyo * WW;
        const int  kR   = h.kR, kRWW = h.kRWW;
        const bool wok  = (lane < kRWW);
        const int  CG   = h.CG;

        for (int g0 = 0; g0 < CPB; g0 += CG) {
            const int gn = min(CG, CPB - g0);
            if (g0) __syncthreads();

            for (int c = wid; c < gn; c += 4) {
                const float* __restrict__ f = base + (size_t)(g0 + c) * HW
                                                   + (size_t)h.y_lo * H + h.x_lo;
                for (int p = 0; p * kR < WH; ++p) {
                    const int row = p * kR + wyo;
                    if (wok && row < WH) {
                        __builtin_amdgcn_global_load_lds(
                            (const __attribute__((address_space(1))) void*)(f + row * H + wxl),
                            (__attribute__((address_space(3))) void*)&win[c * SLOT + p * kRWW],
                            4, 0, 0);
                    }
                }
            }
            __syncthreads();               // vmcnt(0) drain: windows resident

            if (smp) {
                for (int c = sub; c < gn; c += NSUB) {
                    const int sb = c * SLOT;
                    fx4 r;
                    #pragma unroll
                    for (int j = 0; j < 4; ++j) {
                        const int a = sb + a0[j];
                        const float v00 = win[a];
                        const float v01 = win[a + 1];
                        const float v10 = win[a + WW];
                        const float v11 = win[a + WW + 1];
                        r[j] = v00 * w00[j] + v01 * w01[j]
                             + v10 * w10[j] + v11 * w11[j];
                    }
                    *reinterpret_cast<fx4*>(opq + (size_t)(g0 + c) * NPOS) = r;
                }
            }
        }
    } else {
        // direct fallback (recompute from props; not expected to fire)
        if (tid < NPOS) {
            const float bx0 = props[n * 7 + 1];
            const float by0 = props[n * 7 + 2];
            const float bx1 = props[n * 7 + 3];
            const float by1 = props[n * 7 + 4];
            const float scale = 0.25f / (float)(1 << h.lvl);
            const float xs0 = bx0 * scale, xs1 = bx1 * scale;
            const float ys0 = by0 * scale, ys1 = by1 * scale;

            const int pos = tid;
            const int py  = pos / CROP;
            const int px  = pos - py * CROP;

            const float gy  = (float)py / 13.0f;
            const float ysv = ys0 + (ys1 - ys0) * gy;
            const float yfv = floorf(ysv);
            const float ly  = ysv - yfv;
            const int   yi0 = min((int)yfv, H - 1);
            const float gx  = (float)px / 13.0f;
            const float xsv = xs0 + (xs1 - xs0) * gx;
            const float xfv = floorf(xsv);
            const float lx  = xsv - xfv;
            const int   xi0 = min((int)xfv, H - 1);

            const int yi1 = min(yi0 + 1, H - 1);
            const int xi1 = min(xi0 + 1, H - 1);
            const int o00 = yi0 * H + xi0;
            const int o01 = yi0 * H + xi1;
            const int o10 = yi1 * H + xi0;
            const int o11 = yi1 * H + xi1;
            const float omy = 1.0f - ly, omx = 1.0f - lx;
            const float w00 = omy * omx, w01 = omy * lx;
            const float w10 = ly * omx,  w11 = ly * lx;

            #pragma unroll 4
            for (int c = 0; c < CPB; ++c) {
                const float* __restrict__ f = base + (size_t)c * HW;
                const float v = f[o00] * w00 + f[o01] * w01
                              + f[o10] * w10 + f[o11] * w11;
                outp[(size_t)c * NPOS + pos] = v;
            }
        }
    }
}

// ---------------- Fallback: R13 kernel verbatim (if ws too small) ---------
__global__ __launch_bounds__(256) void crop_roi_fallback(
    const float* __restrict__ p2, const float* __restrict__ p3,
    const float* __restrict__ p4, const float* __restrict__ p5,
    const float* __restrict__ props, float* __restrict__ out)
{
    const int blk   = blockIdx.x;
    const int n     = blk >> 4;
    const int chunk = blk & 15;
    const int tid   = threadIdx.x;
    const int lane  = tid & 63;
    const int wid   = tid >> 6;

    __shared__ float win[LDS_FLOATS];

    const int   bimg = (int)props[n * 7 + 0];
    const float bx0  = props[n * 7 + 1];
    const float by0  = props[n * 7 + 2];
    const float bx1  = props[n * 7 + 3];
    const float by1  = props[n * 7 + 4];

    const float sz = sqrtf((bx1 - bx0) * (by1 - by0));
    int lvl = 0; float bd = fabsf(sz - 8.0f), d;
    d = fabsf(sz - 16.0f); if (d < bd) { bd = d; lvl = 1; }
    d = fabsf(sz - 32.0f); if (d < bd) { bd = d; lvl = 2; }
    d = fabsf(sz - 64.0f); if (d < bd) { bd = d; lvl = 3; }

    const int   H     = 256 >> lvl;
    const int   HW    = H * H;
    const float scale = 0.25f / (float)(1 << lvl);
    const float* fp   = (lvl == 0) ? p2 : (lvl == 1) ? p3 : (lvl == 2) ? p4 : p5;
    const float* base = fp + (size_t)bimg * CHANNELS * HW
                           + (size_t)(chunk * CPB) * HW;

    const float xs0 = bx0 * scale, xs1 = bx1 * scale;
    const float ys0 = by0 * scale, ys1 = by1 * scale;
    const int x_lo = min((int)floorf(xs0), H - 2);
    const int x_hi = min((int)floorf(xs1), H - 2) + 1;
    const int y_lo = min((int)floorf(ys0), H - 2);
    const int y_hi = min((int)floorf(ys1), H - 2) + 1;
    const int WW = x_hi - x_lo + 1;
    const int WH = y_hi - y_lo + 1;
    const int SLOT = WH * WW;

    float* __restrict__ outp = out + ((size_t)n * CHANNELS + chunk * CPB) * NPOS;

    if (SLOT <= SLOT_MAX) {
        const int q   = tid % NQUAD;
        const int sub = tid / NQUAD;
        const bool smp = (sub < NSUB);

        float w00[4], w01[4], w10[4], w11[4];
        int   a0[4];
        #pragma unroll
        for (int j = 0; j < 4; ++j) {
            const int p  = 4 * q + j;
            const int py = p / CROP;
            const int px = p - py * CROP;

            const float gy  = (float)py / 13.0f;
            const float ysv = ys0 + (ys1 - ys0) * gy;
            const float yfv = floorf(ysv);
            const float ly  = ysv - yfv;
            const int   yi0 = min((int)yfv, H - 1);
            const bool  ycl = (yi0 == H - 1);
            const int   byl = (ycl ? H - 2 : yi0) - y_lo;
            const float wy0 = ycl ? 0.0f : 1.0f - ly;
            const float wy1 = ycl ? 1.0f : ly;

            const float gx  = (float)px / 13.0f;
            const float xsv = xs0 + (xs1 - xs0) * gx;
            const float xfv = floorf(xsv);
            const float lx  = xsv - xfv;
            const int   xi0 = min((int)xfv, H - 1);
            const bool  xcl = (xi0 == H - 1);
            const int   bxl = (xcl ? H - 2 : xi0) - x_lo;
            const float wx0 = xcl ? 0.0f : 1.0f - lx;
            const float wx1 = xcl ? 1.0f : lx;

            a0[j]  = byl * WW + bxl;
            w00[j] = wy0 * wx0; w01[j] = wy0 * wx1;
            w10[j] = wy1 * wx0; w11[j] = wy1 * wx1;
        }
        float* __restrict__ opq = outp + 4 * q;

        int CG = LDS_FLOATS / SLOT; if (CG > CPB) CG = CPB;

        const int  wyo  = lane / WW;
        const int  wxl  = lane - wyo * WW;
        const int  kR   = 64 / WW;
        const int  kRWW = kR * WW;
        const bool wok  = (lane < kRWW);

        for (int g0 = 0; g0 < CPB; g0 += CG) {
            const int gn = min(CG, CPB - g0);
            if (g0) __syncthreads();

            for (int c = wid; c < gn; c += 4) {
                const float* __restrict__ f = base + (size_t)(g0 + c) * HW
                                                   + (size_t)y_lo * H + x_lo;
                for (int p = 0; p * kR < WH; ++p) {
                    const int row = p * kR + wyo;
                    if (wok && row < WH) {
                        __builtin_amdgcn_global_load_lds(
                            (const __attribute__((address_space(1))) void*)(f + row * H + wxl),
                            (__attribute__((address_space(3))) void*)&win[c * SLOT + p * kRWW],
                            4, 0, 0);
                    }
                }
            }
            __syncthreads();

            if (smp) {
                for (int c = sub; c < gn; c += NSUB) {
                    const int sb = c * SLOT;
                    fx4 r;
                    #pragma unroll
                    for (int j = 0; j < 4; ++j) {
                        const int a = sb + a0[j];
                        const float v00 = win[a];
                        const float v01 = win[a + 1];
                        const float v10 = win[a + WW];
                        const float v11 = win[a + WW + 1];
                        r[j] = v00 * w00[j] + v01 * w01[j]
                             + v10 * w10[j] + v11 * w11[j];
                    }
                    *reinterpret_cast<fx4*>(opq + (size_t)(g0 + c) * NPOS) = r;
                }
            }
        }
    } else {
        if (tid < NPOS) {
            const int pos = tid;
            const int py  = pos / CROP;
            const int px  = pos - py * CROP;

            const float gy  = (float)py / 13.0f;
            const float ysv = ys0 + (ys1 - ys0) * gy;
            const float yfv = floorf(ysv);
            const float ly  = ysv - yfv;
            const int   yi0 = min((int)yfv, H - 1);
            const float gx  = (float)px / 13.0f;
            const float xsv = xs0 + (xs1 - xs0) * gx;
            const float xfv = floorf(xsv);
            const float lx  = xsv - xfv;
            const int   xi0 = min((int)xfv, H - 1);

            const int yi1 = min(yi0 + 1, H - 1);
            const int xi1 = min(xi0 + 1, H - 1);
            const int o00 = yi0 * H + xi0;
            const int o01 = yi0 * H + xi1;
            const int o10 = yi1 * H + xi0;
            const int o11 = yi1 * H + xi1;
            const float omy = 1.0f - ly, omx = 1.0f - lx;
            const float w00 = omy * omx, w01 = omy * lx;
            const float w10 = ly * omx,  w11 = ly * lx;

            #pragma unroll 4
            for (int c = 0; c < CPB; ++c) {
                const float* __restrict__ f = base + (size_t)c * HW;
                const float v = f[o00] * w00 + f[o01] * w01
                              + f[o10] * w10 + f[o11] * w11;
                outp[(size_t)c * NPOS + pos] = v;
            }
        }
    }
}

extern "C" void kernel_launch(void* const* d_in, const int* in_sizes, int n_in,
                              void* d_out, int out_size, void* d_ws, size_t ws_size,
                              hipStream_t stream) {
    const float* p2    = (const float*)d_in[0];
    const float* p3    = (const float*)d_in[1];
    const float* p4    = (const float*)d_in[2];
    const float* p5    = (const float*)d_in[3];
    const float* props = (const float*)d_in[4];
    float* outp        = (float*)d_out;

    const int N = in_sizes[4] / 7;          // 1024 proposals
    const size_t need = (size_t)N * TBL_STRIDE;

    if (ws_size >= need) {
        hipLaunchKernelGGL(precompute_kernel, dim3(N), dim3(256), 0, stream,
                           props, (char*)d_ws);
        hipLaunchKernelGGL(crop_roi_main, dim3(N * NBLK), dim3(256), 0, stream,
                           p2, p3, p4, p5, props, (const char*)d_ws, outp);
    } else {
        hipLaunchKernelGGL(crop_roi_fallback, dim3(N * NBLK), dim3(256), 0, stream,
                           p2, p3, p4, p5, props, outp);
    }
}

// Round 15
// 68.031 us; speedup vs baseline: 1.0114x; 1.0114x over previous
//
#include <hip/hip_runtime.h>

#define CROP 14
#define NPOS (CROP * CROP)       // 196
#define CHANNELS 256
#define CPB 16                   // channels per block (16 blocks per proposal)
#define NBLK (CHANNELS / CPB)    // 16
#define CPW 4                    // channels per wave (4 waves x 4 = 16)
#define WVF 1024                 // LDS floats per wave (4 KB; block = 16 KB)
#define NQUAD 49

typedef float __attribute__((ext_vector_type(4))) fx4;

// Block = (proposal, 16-channel slice); WAVE = 4 channels, fully autonomous:
// stage own windows into private LDS quarter via global_load_lds, per-wave
// s_waitcnt vmcnt(0) (NO __syncthreads anywhere), sample, dwordx4 stores.
__global__ __launch_bounds__(256) void crop_roi_kernel(
    const float* __restrict__ p2, const float* __restrict__ p3,
    const float* __restrict__ p4, const float* __restrict__ p5,
    const float* __restrict__ props, float* __restrict__ out)
{
    const int blk   = blockIdx.x;
    const int n     = blk >> 4;            // proposal
    const int chunk = blk & 15;            // 16-channel slice
    const int tid   = threadIdx.x;
    const int lane  = tid & 63;
    const int wid   = tid >> 6;

    __shared__ float win[4 * WVF];
    float* __restrict__ wbase = &win[wid * WVF];   // this wave's private 4 KB

    // ---- proposal setup (uniform; computed redundantly per thread) ----
    const int   bimg = (int)props[n * 7 + 0];
    const float bx0  = props[n * 7 + 1];
    const float by0  = props[n * 7 + 2];
    const float bx1  = props[n * 7 + 3];
    const float by1  = props[n * 7 + 4];

    const float sz = sqrtf((bx1 - bx0) * (by1 - by0));
    int lvl = 0; float bd = fabsf(sz - 8.0f), d;
    d = fabsf(sz - 16.0f); if (d < bd) { bd = d; lvl = 1; }
    d = fabsf(sz - 32.0f); if (d < bd) { bd = d; lvl = 2; }
    d = fabsf(sz - 64.0f); if (d < bd) { bd = d; lvl = 3; }

    const int   H     = 256 >> lvl;                 // H == W
    const int   HW    = H * H;
    const float scale = 0.25f / (float)(1 << lvl);  // exact
    const float* fp   = (lvl == 0) ? p2 : (lvl == 1) ? p3 : (lvl == 2) ? p4 : p5;
    // this wave's first channel: chunk*CPB + wid*CPW
    const float* wchan = fp + (size_t)bimg * CHANNELS * HW
                            + (size_t)(chunk * CPB + wid * CPW) * HW;

    // ---- window bounds (uniform) ----
    const float xs0 = bx0 * scale, xs1 = bx1 * scale;
    const float ys0 = by0 * scale, ys1 = by1 * scale;
    const int x_lo = min((int)floorf(xs0), H - 2);
    const int x_hi = min((int)floorf(xs1), H - 2) + 1;
    const int y_lo = min((int)floorf(ys0), H - 2);
    const int y_hi = min((int)floorf(ys1), H - 2) + 1;
    const int WW = x_hi - x_lo + 1;
    const int WH = y_hi - y_lo + 1;
    const int SLOT = WH * WW;              // floats per channel window (<=~330)

    float* __restrict__ outp = out + ((size_t)n * CHANNELS
                                      + chunk * CPB + wid * CPW) * NPOS;

    if (SLOT <= WVF) {
        // ---- per-lane quad params (lane<49 meaningful; clamp for the rest) ----
        const int q = (lane < NQUAD) ? lane : 0;
        int a0[4]; float w00[4], w01[4], w10[4], w11[4];
        #pragma unroll
        for (int j = 0; j < 4; ++j) {
            const int p  = 4 * q + j;
            const int py = p / CROP;
            const int px = p - py * CROP;

            const float gy  = (float)py / 13.0f;
            const float ysv = ys0 + (ys1 - ys0) * gy;
            const float yfv = floorf(ysv);
            const float ly  = ysv - yfv;                  // unclamped (ref)
            const int   yi0 = min((int)yfv, H - 1);       // ysv >= 0
            const bool  ycl = (yi0 == H - 1);
            const int   byl = (ycl ? H - 2 : yi0) - y_lo;
            const float wy0 = ycl ? 0.0f : 1.0f - ly;
            const float wy1 = ycl ? 1.0f : ly;

            const float gx  = (float)px / 13.0f;
            const float xsv = xs0 + (xs1 - xs0) * gx;
            const float xfv = floorf(xsv);
            const float lx  = xsv - xfv;
            const int   xi0 = min((int)xfv, H - 1);
            const bool  xcl = (xi0 == H - 1);
            const int   bxl = (xcl ? H - 2 : xi0) - x_lo;
            const float wx0 = xcl ? 0.0f : 1.0f - lx;
            const float wx1 = xcl ? 1.0f : lx;

            a0[j]  = byl * WW + bxl;
            w00[j] = wy0 * wx0;
            w01[j] = wy0 * wx1;
            w10[j] = wy1 * wx0;
            w11[j] = wy1 * wx1;
        }

        // ---- staging lane geometry (lane-linear LDS dest contract) ----
        const int  wyo  = lane / WW;
        const int  wxl  = lane - wyo * WW;
        const int  kR   = 64 / WW;           // full rows per pass (>=2)
        const int  kRWW = kR * WW;
        const bool wok  = (lane < kRWW);

        int CGW = WVF / SLOT; if (CGW > CPW) CGW = CPW;  // usually 4

        for (int g0 = 0; g0 < CPW; g0 += CGW) {
            const int gn = min(CGW, CPW - g0);

            // stage this wave's channels (async -> private LDS region)
            for (int c = 0; c < gn; ++c) {
                const float* __restrict__ f = wchan + (size_t)(g0 + c) * HW
                                                    + (size_t)y_lo * H + x_lo;
                for (int p = 0; p * kR < WH; ++p) {
                    const int row = p * kR + wyo;
                    if (wok && row < WH) {
                        __builtin_amdgcn_global_load_lds(
                            (const __attribute__((address_space(1))) void*)(f + row * H + wxl),
                            (__attribute__((address_space(3))) void*)&wbase[c * SLOT + p * kRWW],
                            4, 0, 0);
                    }
                }
            }
            // per-wave drain; no __syncthreads (LDS region is wave-private)
            asm volatile("s_waitcnt vmcnt(0)" ::: "memory");

            if (lane < NQUAD) {
                for (int c = 0; c < gn; ++c) {
                    const int sb = c * SLOT;
                    fx4 r;
                    #pragma unroll
                    for (int j = 0; j < 4; ++j) {
                        const int a = sb + a0[j];
                        const float v00 = wbase[a];
                        const float v01 = wbase[a + 1];       // ds_read2 pair
                        const float v10 = wbase[a + WW];
                        const float v11 = wbase[a + WW + 1];  // ds_read2 pair
                        r[j] = v00 * w00[j] + v01 * w01[j]
                             + v10 * w10[j] + v11 * w11[j];
                    }
                    *reinterpret_cast<fx4*>(outp + (size_t)(g0 + c) * NPOS + 4 * q) = r;
                }
            }
        }
    } else {
        // ---- direct fallback (safety; geometry keeps SLOT <= ~330) ----
        if (lane < NQUAD) {
            const int q = lane;
            #pragma unroll
            for (int j = 0; j < 4; ++j) {
                const int p  = 4 * q + j;
                const int py = p / CROP;
                const int px = p - py * CROP;

                const float gy  = (float)py / 13.0f;
                const float ysv = ys0 + (ys1 - ys0) * gy;
                const float yfv = floorf(ysv);
                const float ly  = ysv - yfv;
                const int   yi0 = min((int)yfv, H - 1);
                const float gx  = (float)px / 13.0f;
                const float xsv = xs0 + (xs1 - xs0) * gx;
                const float xfv = floorf(xsv);
                const float lx  = xsv - xfv;
                const int   xi0 = min((int)xfv, H - 1);

                const int yi1 = min(yi0 + 1, H - 1);
                const int xi1 = min(xi0 + 1, H - 1);
                const int o00 = yi0 * H + xi0;
                const int o01 = yi0 * H + xi1;
                const int o10 = yi1 * H + xi0;
                const int o11 = yi1 * H + xi1;
                const float omy = 1.0f - ly, omx = 1.0f - lx;
                const float w00 = omy * omx, w01 = omy * lx;
                const float w10 = ly * omx,  w11 = ly * lx;

                for (int c = 0; c < CPW; ++c) {
                    const float* __restrict__ f = wchan + (size_t)c * HW;
                    const float v = f[o00] * w00 + f[o01] * w01
                                  + f[o10] * w10 + f[o11] * w11;
                    outp[(size_t)c * NPOS + p] = v;
                }
            }
        }
    }
}

extern "C" void kernel_launch(void* const* d_in, const int* in_sizes, int n_in,
                              void* d_out, int out_size, void* d_ws, size_t ws_size,
                              hipStream_t stream) {
    const float* p2    = (const float*)d_in[0];
    const float* p3    = (const float*)d_in[1];
    const float* p4    = (const float*)d_in[2];
    const float* p5    = (const float*)d_in[3];
    const float* props = (const float*)d_in[4];
    float* outp        = (float*)d_out;

    const int N = in_sizes[4] / 7;          // 1024 proposals
    dim3 grid(N * NBLK);                    // 16384 blocks
    dim3 block(256);
    hipLaunchKernelGGL(crop_roi_kernel, grid, block, 0, stream,
                       p2, p3, p4, p5, props, outp);
}

// Round 16
// 64.745 us; speedup vs baseline: 1.0627x; 1.0507x over previous
//
#include <hip/hip_runtime.h>

#define CROP 14
#define NPOS (CROP * CROP)       // 196
#define CHANNELS 256
#define CPB 16                   // channels per block (16 blocks per proposal)
#define NBLK (CHANNELS / CPB)    // 16
#define LDS_FLOATS 4096          // 16 KiB -> 8 blocks/CU
#define SLOT_MAX 392             // fallback threshold (geometry keeps SLOT below)
#define NQUAD 49
#define NSUB 5                   // 5*49 = 245 active sample threads

typedef float __attribute__((ext_vector_type(4))) fx4;

// Block = (proposal, 16-channel slice). Stage all 16 ROI windows via async
// global_load_lds; compute per-thread quad params WHILE loads are in flight;
// one __syncthreads drain; sample quads + dwordx4 stores. (R13 + reorder.)
__global__ __launch_bounds__(256, 8) void crop_roi_kernel(
    const float* __restrict__ p2, const float* __restrict__ p3,
    const float* __restrict__ p4, const float* __restrict__ p5,
    const float* __restrict__ props, float* __restrict__ out)
{
    const int blk   = blockIdx.x;
    const int n     = blk >> 4;            // proposal
    const int chunk = blk & 15;            // 16-channel slice
    const int tid   = threadIdx.x;
    const int lane  = tid & 63;
    const int wid   = tid >> 6;

    __shared__ float win[LDS_FLOATS];

    // ---- proposal setup (uniform across block; computed redundantly) ----
    const int   bimg = (int)props[n * 7 + 0];
    const float bx0  = props[n * 7 + 1];
    const float by0  = props[n * 7 + 2];
    const float bx1  = props[n * 7 + 3];
    const float by1  = props[n * 7 + 4];

    const float sz = sqrtf((bx1 - bx0) * (by1 - by0));
    int lvl = 0; float bd = fabsf(sz - 8.0f), d;
    d = fabsf(sz - 16.0f); if (d < bd) { bd = d; lvl = 1; }
    d = fabsf(sz - 32.0f); if (d < bd) { bd = d; lvl = 2; }
    d = fabsf(sz - 64.0f); if (d < bd) { bd = d; lvl = 3; }

    const int   H     = 256 >> lvl;                 // H == W
    const int   HW    = H * H;
    const float scale = 0.25f / (float)(1 << lvl);  // exact
    const float* fp   = (lvl == 0) ? p2 : (lvl == 1) ? p3 : (lvl == 2) ? p4 : p5;
    const float* base = fp + (size_t)bimg * CHANNELS * HW
                           + (size_t)(chunk * CPB) * HW;

    // ---- window bounds (uniform) ----
    const float xs0 = bx0 * scale, xs1 = bx1 * scale;
    const float ys0 = by0 * scale, ys1 = by1 * scale;
    const int x_lo = min((int)floorf(xs0), H - 2);
    const int x_hi = min((int)floorf(xs1), H - 2) + 1;
    const int y_lo = min((int)floorf(ys0), H - 2);
    const int y_hi = min((int)floorf(ys1), H - 2) + 1;
    const int WW = x_hi - x_lo + 1;
    const int WH = y_hi - y_lo + 1;
    const int SLOT = WH * WW;              // floats per channel window

    float* __restrict__ outp = out + ((size_t)n * CHANNELS + chunk * CPB) * NPOS;

    if (SLOT <= SLOT_MAX) {
        // ---- staging lane geometry (needed before load issue) ----
        const int  wyo  = lane / WW;
        const int  wxl  = lane - wyo * WW;
        const int  kR   = 64 / WW;           // full rows per pass (>=2)
        const int  kRWW = kR * WW;
        const bool wok  = (lane < kRWW);

        int CG = LDS_FLOATS / SLOT; if (CG > CPB) CG = CPB;  // >= 10 always
        const int gn0 = min(CG, CPB);

        // ---- ISSUE stage loads for group 0 FIRST (async -> LDS) ----
        for (int c = wid; c < gn0; c += 4) {
            const float* __restrict__ f = base + (size_t)c * HW
                                               + (size_t)y_lo * H + x_lo;
            for (int p = 0; p * kR < WH; ++p) {
                const int row = p * kR + wyo;
                if (wok && row < WH) {
                    __builtin_amdgcn_global_load_lds(
                        (const __attribute__((address_space(1))) void*)(f + row * H + wxl),
                        (__attribute__((address_space(3))) void*)&win[c * SLOT + p * kRWW],
                        4, 0, 0);
                }
            }
        }

        // ---- quad params computed WHILE group-0 loads are in flight ----
        const int q   = tid % NQUAD;       // quad index (pos 4q..4q+3)
        const int sub = tid / NQUAD;       // channel substream 0..4 (5=idle)
        const bool smp = (sub < NSUB);

        float w00[4], w01[4], w10[4], w11[4];
        int   a0[4];
        #pragma unroll
        for (int j = 0; j < 4; ++j) {
            const int p  = 4 * q + j;
            const int py = p / CROP;
            const int px = p - py * CROP;

            const float gy  = (float)py / 13.0f;
            const float ysv = ys0 + (ys1 - ys0) * gy;
            const float yfv = floorf(ysv);
            const float ly  = ysv - yfv;                  // unclamped (ref)
            const int   yi0 = min((int)yfv, H - 1);       // ysv >= 0
            const bool  ycl = (yi0 == H - 1);
            const int   byl = (ycl ? H - 2 : yi0) - y_lo;
            const float wy0 = ycl ? 0.0f : 1.0f - ly;
            const float wy1 = ycl ? 1.0f : ly;

            const float gx  = (float)px / 13.0f;
            const float xsv = xs0 + (xs1 - xs0) * gx;
            const float xfv = floorf(xsv);
            const float lx  = xsv - xfv;
            const int   xi0 = min((int)xfv, H - 1);
            const bool  xcl = (xi0 == H - 1);
            const int   bxl = (xcl ? H - 2 : xi0) - x_lo;
            const float wx0 = xcl ? 0.0f : 1.0f - lx;
            const float wx1 = xcl ? 1.0f : lx;

            a0[j]  = byl * WW + bxl;
            w00[j] = wy0 * wx0;
            w01[j] = wy0 * wx1;
            w10[j] = wy1 * wx0;
            w11[j] = wy1 * wx1;
        }
        float* __restrict__ opq = outp + 4 * q;

        // ---- group loop (group 0's loads already issued above) ----
        for (int g0 = 0; g0 < CPB; g0 += CG) {
            const int gn = min(CG, CPB - g0);

            if (g0) {
                __syncthreads();           // rare 2nd group: protect reads
                for (int c = wid; c < gn; c += 4) {
                    const float* __restrict__ f = base + (size_t)(g0 + c) * HW
                                                       + (size_t)y_lo * H + x_lo;
                    for (int p = 0; p * kR < WH; ++p) {
                        const int row = p * kR + wyo;
                        if (wok && row < WH) {
                            __builtin_amdgcn_global_load_lds(
                                (const __attribute__((address_space(1))) void*)(f + row * H + wxl),
                                (__attribute__((address_space(3))) void*)&win[c * SLOT + p * kRWW],
                                4, 0, 0);
                        }
                    }
                }
            }
            __syncthreads();               // vmcnt(0) drain: windows resident

            if (smp) {
                for (int c = sub; c < gn; c += NSUB) {
                    const int sb = c * SLOT;
                    fx4 r;
                    #pragma unroll
                    for (int j = 0; j < 4; ++j) {
                        const int a = sb + a0[j];
                        const float v00 = win[a];
                        const float v01 = win[a + 1];       // ds_read2 pair
                        const float v10 = win[a + WW];
                        const float v11 = win[a + WW + 1];  // ds_read2 pair
                        r[j] = v00 * w00[j] + v01 * w01[j]
                             + v10 * w10[j] + v11 * w11[j];
                    }
                    *reinterpret_cast<fx4*>(opq + (size_t)(g0 + c) * NPOS) = r;
                }
            }
        }
    } else {
        // ================= direct fallback (safety; not expected) ==========
        if (tid < NPOS) {
            const int pos = tid;
            const int py  = pos / CROP;
            const int px  = pos - py * CROP;

            const float gy  = (float)py / 13.0f;
            const float ysv = ys0 + (ys1 - ys0) * gy;
            const float yfv = floorf(ysv);
            const float ly  = ysv - yfv;
            const int   yi0 = min((int)yfv, H - 1);
            const float gx  = (float)px / 13.0f;
            const float xsv = xs0 + (xs1 - xs0) * gx;
            const float xfv = floorf(xsv);
            const float lx  = xsv - xfv;
            const int   xi0 = min((int)xfv, H - 1);

            const int yi1 = min(yi0 + 1, H - 1);
            const int xi1 = min(xi0 + 1, H - 1);
            const int o00 = yi0 * H + xi0;
            const int o01 = yi0 * H + xi1;
            const int o10 = yi1 * H + xi0;
            const int o11 = yi1 * H + xi1;
            const float omy = 1.0f - ly, omx = 1.0f - lx;
            const float w00 = omy * omx, w01 = omy * lx;
            const float w10 = ly * omx,  w11 = ly * lx;

            #pragma unroll 4
            for (int c = 0; c < CPB; ++c) {
                const float* __restrict__ f = base + (size_t)c * HW;
                const float v = f[o00] * w00 + f[o01] * w01
                              + f[o10] * w10 + f[o11] * w11;
                outp[(size_t)c * NPOS + pos] = v;
            }
        }
    }
}

extern "C" void kernel_launch(void* const* d_in, const int* in_sizes, int n_in,
                              void* d_out, int out_size, void* d_ws, size_t ws_size,
                              hipStream_t stream) {
    const float* p2    = (const float*)d_in[0];
    const float* p3    = (const float*)d_in[1];
    const float* p4    = (const float*)d_in[2];
    const float* p5    = (const float*)d_in[3];
    const float* props = (const float*)d_in[4];
    float* outp        = (float*)d_out;

    const int N = in_sizes[4] / 7;          // 1024 proposals
    dim3 grid(N * NBLK);                    // 16384 blocks
    dim3 block(256);
    hipLaunchKernelGGL(crop_roi_kernel, grid, block, 0, stream,
                       p2, p3, p4, p5, props, outp);
}

// Round 17
// 61.567 us; speedup vs baseline: 1.1175x; 1.0516x over previous
//
#include <hip/hip_runtime.h>

#define CROP 14
#define NPOS (CROP * CROP)       // 196
#define CHANNELS 256
#define CPB 16                   // channels per block (16 blocks per proposal)
#define NBLK (CHANNELS / CPB)    // 16
#define WIN_FLOATS 3584          // 14 KiB window buffer
#define SLOT_MAX 392             // fallback threshold (geometry keeps SLOT <= ~340)
#define NQUAD 49
#define NSUB 5                   // 5*49 = 245 active sample threads

typedef float __attribute__((ext_vector_type(4))) fx4;

// Block = (proposal, 16-channel slice).
// 1) issue async global_load_lds for the ROI windows
// 2) WHILE loads fly: tid<196 each computes ONE position's bilinear entry
//    (addr + 4 premultiplied weights) into an LDS table
// 3) one __syncthreads drain (covers stage loads AND table writes)
// 4) sample: read 4 table entries, 8 ds_read2 + 16 FMA + dwordx4 store/channel
__global__ __launch_bounds__(256) void crop_roi_kernel(
    const float* __restrict__ p2, const float* __restrict__ p3,
    const float* __restrict__ p4, const float* __restrict__ p5,
    const float* __restrict__ props, float* __restrict__ out)
{
    const int blk   = blockIdx.x;
    const int n     = blk >> 4;            // proposal
    const int chunk = blk & 15;            // 16-channel slice
    const int tid   = threadIdx.x;
    const int lane  = tid & 63;
    const int wid   = tid >> 6;

    __shared__ float win[WIN_FLOATS];
    __shared__ fx4   wtab[NPOS];           // packed weights per position
    __shared__ int   atab[NPOS];           // slot-local corner address

    // ---- proposal setup (uniform across block; computed redundantly) ----
    const int   bimg = (int)props[n * 7 + 0];
    const float bx0  = props[n * 7 + 1];
    const float by0  = props[n * 7 + 2];
    const float bx1  = props[n * 7 + 3];
    const float by1  = props[n * 7 + 4];

    const float sz = sqrtf((bx1 - bx0) * (by1 - by0));
    int lvl = 0; float bd = fabsf(sz - 8.0f), d;
    d = fabsf(sz - 16.0f); if (d < bd) { bd = d; lvl = 1; }
    d = fabsf(sz - 32.0f); if (d < bd) { bd = d; lvl = 2; }
    d = fabsf(sz - 64.0f); if (d < bd) { bd = d; lvl = 3; }

    const int   H     = 256 >> lvl;                 // H == W
    const int   HW    = H * H;
    const float scale = 0.25f / (float)(1 << lvl);  // exact
    const float* fp   = (lvl == 0) ? p2 : (lvl == 1) ? p3 : (lvl == 2) ? p4 : p5;
    const float* base = fp + (size_t)bimg * CHANNELS * HW
                           + (size_t)(chunk * CPB) * HW;

    // ---- window bounds (uniform) ----
    const float xs0 = bx0 * scale, xs1 = bx1 * scale;
    const float ys0 = by0 * scale, ys1 = by1 * scale;
    const int x_lo = min((int)floorf(xs0), H - 2);
    const int x_hi = min((int)floorf(xs1), H - 2) + 1;
    const int y_lo = min((int)floorf(ys0), H - 2);
    const int y_hi = min((int)floorf(ys1), H - 2) + 1;
    const int WW = x_hi - x_lo + 1;
    const int WH = y_hi - y_lo + 1;
    const int SLOT = WH * WW;              // floats per channel window

    float* __restrict__ outp = out + ((size_t)n * CHANNELS + chunk * CPB) * NPOS;

    if (SLOT <= SLOT_MAX) {
        // ---- staging lane geometry ----
        const int  wyo  = lane / WW;
        const int  wxl  = lane - wyo * WW;
        const int  kR   = 64 / WW;           // full rows per pass (>=2)
        const int  kRWW = kR * WW;
        const bool wok  = (lane < kRWW);

        int CG = WIN_FLOATS / SLOT; if (CG > CPB) CG = CPB;  // >= 9 always
        const int gn0 = min(CG, CPB);

        // ---- ISSUE stage loads for group 0 FIRST (async -> LDS) ----
        for (int c = wid; c < gn0; c += 4) {
            const float* __restrict__ f = base + (size_t)c * HW
                                               + (size_t)y_lo * H + x_lo;
            for (int p = 0; p * kR < WH; ++p) {
                const int row = p * kR + wyo;
                if (wok && row < WH) {
                    __builtin_amdgcn_global_load_lds(
                        (const __attribute__((address_space(1))) void*)(f + row * H + wxl),
                        (__attribute__((address_space(3))) void*)&win[c * SLOT + p * kRWW],
                        4, 0, 0);
                }
            }
        }

        // ---- build the per-position table WHILE loads are in flight ----
        if (tid < NPOS) {
            const int py = tid / CROP;
            const int px = tid - py * CROP;

            const float gy  = (float)py / 13.0f;
            const float ysv = ys0 + (ys1 - ys0) * gy;
            const float yfv = floorf(ysv);
            const float ly  = ysv - yfv;                  // unclamped (ref)
            const int   yi0 = min((int)yfv, H - 1);       // ysv >= 0
            const bool  ycl = (yi0 == H - 1);
            const int   byl = (ycl ? H - 2 : yi0) - y_lo;
            const float wy0 = ycl ? 0.0f : 1.0f - ly;
            const float wy1 = ycl ? 1.0f : ly;

            const float gx  = (float)px / 13.0f;
            const float xsv = xs0 + (xs1 - xs0) * gx;
            const float xfv = floorf(xsv);
            const float lx  = xsv - xfv;
            const int   xi0 = min((int)xfv, H - 1);
            const bool  xcl = (xi0 == H - 1);
            const int   bxl = (xcl ? H - 2 : xi0) - x_lo;
            const float wx0 = xcl ? 0.0f : 1.0f - lx;
            const float wx1 = xcl ? 1.0f : lx;

            fx4 w;
            w.x = wy0 * wx0;   // w00
            w.y = wy0 * wx1;   // w01
            w.z = wy1 * wx0;   // w10
            w.w = wy1 * wx1;   // w11
            wtab[tid] = w;
            atab[tid] = byl * WW + bxl;
        }

        const int q   = tid % NQUAD;       // quad index (pos 4q..4q+3)
        const int sub = tid / NQUAD;       // channel substream 0..4 (5=idle)
        const bool smp = (sub < NSUB);
        float* __restrict__ opq = outp + 4 * q;

        // ---- group loop (group 0's loads already issued above) ----
        bool have_params = false;
        fx4 wj[4]; int a0[4];

        for (int g0 = 0; g0 < CPB; g0 += CG) {
            const int gn = min(CG, CPB - g0);

            if (g0) {
                __syncthreads();           // rare 2nd group: protect reads
                for (int c = wid; c < gn; c += 4) {
                    const float* __restrict__ f = base + (size_t)(g0 + c) * HW
                                                       + (size_t)y_lo * H + x_lo;
                    for (int p = 0; p * kR < WH; ++p) {
                        const int row = p * kR + wyo;
                        if (wok && row < WH) {
                            __builtin_amdgcn_global_load_lds(
                                (const __attribute__((address_space(1))) void*)(f + row * H + wxl),
                                (__attribute__((address_space(3))) void*)&win[c * SLOT + p * kRWW],
                                4, 0, 0);
                        }
                    }
                }
            }
            __syncthreads();               // drain: windows + table resident

            if (smp) {
                if (!have_params) {        // one-time table read (post-barrier)
                    #pragma unroll
                    for (int j = 0; j < 4; ++j) {
                        wj[j] = wtab[4 * q + j];
                        a0[j] = atab[4 * q + j];
                    }
                    have_params = true;
                }
                for (int c = sub; c < gn; c += NSUB) {
                    const int sb = c * SLOT;
                    fx4 r;
                    #pragma unroll
                    for (int j = 0; j < 4; ++j) {
                        const int a = sb + a0[j];
                        const float v00 = win[a];
                        const float v01 = win[a + 1];       // ds_read2 pair
                        const float v10 = win[a + WW];
                        const float v11 = win[a + WW + 1];  // ds_read2 pair
                        r[j] = v00 * wj[j].x + v01 * wj[j].y
                             + v10 * wj[j].z + v11 * wj[j].w;
                    }
                    *reinterpret_cast<fx4*>(opq + (size_t)(g0 + c) * NPOS) = r;
                }
            }
        }
    } else {
        // ================= direct fallback (safety; not expected) ==========
        if (tid < NPOS) {
            const int pos = tid;
            const int py  = pos / CROP;
            const int px  = pos - py * CROP;

            const float gy  = (float)py / 13.0f;
            const float ysv = ys0 + (ys1 - ys0) * gy;
            const float yfv = floorf(ysv);
            const float ly  = ysv - yfv;
            const int   yi0 = min((int)yfv, H - 1);
            const float gx  = (float)px / 13.0f;
            const float xsv = xs0 + (xs1 - xs0) * gx;
            const float xfv = floorf(xsv);
            const float lx  = xsv - xfv;
            const int   xi0 = min((int)xfv, H - 1);

            const int yi1 = min(yi0 + 1, H - 1);
            const int xi1 = min(xi0 + 1, H - 1);
            const int o00 = yi0 * H + xi0;
            const int o01 = yi0 * H + xi1;
            const int o10 = yi1 * H + xi0;
            const int o11 = yi1 * H + xi1;
            const float omy = 1.0f - ly, omx = 1.0f - lx;
            const float w00 = omy * omx, w01 = omy * lx;
            const float w10 = ly * omx,  w11 = ly * lx;

            #pragma unroll 4
            for (int c = 0; c < CPB; ++c) {
                const float* __restrict__ f = base + (size_t)c * HW;
                const float v = f[o00] * w00 + f[o01] * w01
                              + f[o10] * w10 + f[o11] * w11;
                outp[(size_t)c * NPOS + pos] = v;
            }
        }
    }
}

extern "C" void kernel_launch(void* const* d_in, const int* in_sizes, int n_in,
                              void* d_out, int out_size, void* d_ws, size_t ws_size,
                              hipStream_t stream) {
    const float* p2    = (const float*)d_in[0];
    const float* p3    = (const float*)d_in[1];
    const float* p4    = (const float*)d_in[2];
    const float* p5    = (const float*)d_in[3];
    const float* props = (const float*)d_in[4];
    float* outp        = (float*)d_out;

    const int N = in_sizes[4] / 7;          // 1024 proposals
    dim3 grid(N * NBLK);                    // 16384 blocks
    dim3 block(256);
    hipLaunchKernelGGL(crop_roi_kernel, grid, block, 0, stream,
                       p2, p3, p4, p5, props, outp);
}